// Round 11
// baseline (13352.870 us; speedup 1.0000x reference)
//
#include <hip/hip_runtime.h>
#include <hip/hip_bf16.h>

#define B_  64
#define T_  1024
#define D_  512
#define H_  1024
#define G4H (4 * H_)
#define NWG 256
#define WTH 512                       // 8 waves per WG
#define SENTQ 0x7FC07FC07FC07FC0ull   // bf16 NaN x4: unreachable, |h|<1

typedef __attribute__((ext_vector_type(8))) short bf16x8;
typedef __attribute__((ext_vector_type(4))) float f32x4;

__device__ __forceinline__ short f2bf(float f) {
    union { float f; unsigned int u; } v; v.f = f;
    unsigned int r = v.u + 0x7FFFu + ((v.u >> 16) & 1u);  // RNE
    return (short)(r >> 16);
}
__device__ __forceinline__ float sigmoid_f(float x) { return 1.0f / (1.0f + __expf(-x)); }
__device__ __forceinline__ float tanh_f(float x) {
    float ax = fabsf(x);
    float e  = __expf(-2.0f * ax);
    return copysignf((1.0f - e) / (1.0f + e), x);
}
__device__ __forceinline__ unsigned long long aloadq(const unsigned long long* p) {
    return __hip_atomic_load(p, __ATOMIC_RELAXED, __HIP_MEMORY_SCOPE_AGENT);
}
__device__ __forceinline__ void astoreq(unsigned long long* p, unsigned long long v) {
    __hip_atomic_store(p, v, __ATOMIC_RELAXED, __HIP_MEMORY_SCOPE_AGENT);
}

// init: slot0 = 0.0 (this IS h_0), slots1..3 = sentinel.
__global__ void init_hbuf(unsigned int* p) {
    int i = blockIdx.x * 256 + threadIdx.x;       // 131072 u32
    p[i] = (i < (B_ * H_ / 2)) ? 0u : 0x7FC07FC0u;
}

// R11 = R10 exchange (coalesced sentinel ring, IC agent path) + 8-wave WGs:
// R10's Occupancy=12.4% (1 wave/SIMD) made every chain latency fully serial.
// Now 512 threads/WG, K split 8 ways (h:128, x:64 per wave) -> 2 waves/SIMD
// overlap poll/LDS/store latencies; per-wave serial MFMA chain halves (24).
// Cross-wave reduce via ds_add_f32 into ONE f32 gate tile ([2][16][68]
// ping-pong, zero-after-read) -> LDS fits (137 KB) and ONE barrier/step.
// Ordering: barrier(t)'s implicit vmcnt-drain keeps the R10 proofs intact
// (re-sentinel tail(t) drained at barrier(t+1); conflicting data store is
// after barrier(t+2); adds(t+2) vs reads/zero(t) separated by barrier(t+1)).
__global__ void __launch_bounds__(WTH, 1)
lstm_persistent(const float* __restrict__ x,     // [B,T,D]
                const float* __restrict__ Wx,    // [D,4H]
                const float* __restrict__ Wh,    // [H,4H]
                const float* __restrict__ bias,  // [4H] (i,f,g,o)
                float* __restrict__ y,           // [B,T,H]
                short* __restrict__ h_buf)       // ws: [4][4][128][16][8] bf16
{
    const int wg   = blockIdx.x;
    const int tid  = threadIdx.x;
    const int lane = tid & 63;
    const int wv   = tid >> 6;                    // 0..7
    const int bt   = (wg >> 1) & 3;               // batch group 0..3
    const int jt   = ((wg & 1) << 5) | (wg >> 3); // hidden tile 0..63
    const int j0   = jt * 16;

    const int c    = lane & 15;         // A-row (in-group batch) / B-col
    const int kblk = lane >> 4;         // k-block (8 contiguous k)
    const int b_a  = bt * 16 + c;       // global batch for x A-frags
    const int kh0  = wv * 128;          // wave's K-slice of H (4 ks)
    const int kx0  = wv * 64;           // wave's K-slice of D (2 ks)

    unsigned long long* const hqb = (unsigned long long*)h_buf;

    __shared__ bf16x8 hw[8][4][4][64];  // 128 KB: [wv][gate][ks][lane]
    __shared__ float  gbuf[2][16][68];  // 8.7 KB ping-pong gate tile

    // ---- prologue: h-weights -> LDS (each thread fills/reads its own slot)
#pragma unroll
    for (int g = 0; g < 4; ++g)
#pragma unroll
        for (int ks = 0; ks < 4; ++ks) {
            bf16x8 tf;
#pragma unroll
            for (int e = 0; e < 8; ++e)
                tf[e] = f2bf(Wh[(size_t)(kh0 + ks * 32 + kblk * 8 + e) * G4H
                                + g * H_ + j0 + c]);
            hw[wv][g][ks][lane] = tf;
        }

    // ---- x-weights -> registers (32 VGPRs), pinned vs rematerialization
    bf16x8 wxf[4][2];
#pragma unroll
    for (int g = 0; g < 4; ++g)
#pragma unroll
        for (int ks = 0; ks < 2; ++ks) {
            bf16x8 tf;
#pragma unroll
            for (int e = 0; e < 8; ++e)
                tf[e] = f2bf(Wx[(size_t)(kx0 + ks * 32 + kblk * 8 + e) * G4H
                                + g * H_ + j0 + c]);
            wxf[g][ks] = tf;
        }
#pragma unroll
    for (int g = 0; g < 4; ++g)
#pragma unroll
        for (int ks = 0; ks < 2; ++ks)
            asm volatile("" : "+v"(wxf[g][ks]));

    // ---- zero the gate tiles
    {
        float* gz = &gbuf[0][0][0];
        for (int i = tid; i < 2 * 16 * 68; i += WTH) gz[i] = 0.f;
    }

    // ---- epilogue mapping (waves 0-3 only): thread -> one (batch, hidden)
    const int eb = (tid >> 4) & 15;
    const int ej = tid & 15;
    const float bi  = bias[0 * H_ + j0 + ej];
    const float bfv = bias[1 * H_ + j0 + ej];
    const float bgv = bias[2 * H_ + j0 + ej];
    const float bo  = bias[3 * H_ + j0 + ej];
    const int b_glob = bt * 16 + eb;
    const int j_glob = j0 + ej;

    float cstate = 0.0f;

    // ---- x-part for t=0 (synchronous) + issue x(1) loads
    f32x4 acc[4] = {{0.f,0.f,0.f,0.f},{0.f,0.f,0.f,0.f},
                    {0.f,0.f,0.f,0.f},{0.f,0.f,0.f,0.f}};
    {
        const float* xr = x + ((size_t)b_a * T_ + 0) * D_ + kx0 + kblk * 8;
#pragma unroll
        for (int ks = 0; ks < 2; ++ks) {
            f32x4 lo = *(const f32x4*)(xr + ks * 32);
            f32x4 hi = *(const f32x4*)(xr + ks * 32 + 4);
            bf16x8 xa;
#pragma unroll
            for (int e = 0; e < 4; ++e) { xa[e] = f2bf(lo[e]); xa[e+4] = f2bf(hi[e]); }
#pragma unroll
            for (int g = 0; g < 4; ++g)
                acc[g] = __builtin_amdgcn_mfma_f32_16x16x32_bf16(xa, wxf[g][ks], acc[g], 0, 0, 0);
        }
    }
    f32x4 xl[2], xh[2];
    {
        const float* xr = x + ((size_t)b_a * T_ + 1) * D_ + kx0 + kblk * 8;
#pragma unroll
        for (int ks = 0; ks < 2; ++ks) {
            xl[ks] = *(const f32x4*)(xr + ks * 32);
            xh[ks] = *(const f32x4*)(xr + ks * 32 + 4);
        }
    }
    __syncthreads();   // gbuf zero + hw visible (hw is self-read anyway)

#pragma unroll 1
    for (int t = 0; t < T_; ++t) {
        // ---- poll h_t (data IS the flag), coalesced; 8 qwords per lane ----
        const unsigned long long* hq = hqb
            + ((((size_t)(t & 3) * 4 + bt) * 128 + wv * 16 + kblk) * 16 + c) * 2;
        unsigned long long q[8];
        for (int cap = 1 << 16; cap > 0; --cap) {
#pragma unroll
            for (int ks = 0; ks < 4; ++ks) {
                q[2*ks]   = aloadq(hq + ks * 128);   // ks stride = 4 chunks
                q[2*ks+1] = aloadq(hq + ks * 128 + 1);
            }
            bool mine = true;
#pragma unroll
            for (int i = 0; i < 8; ++i) mine &= (q[i] != SENTQ);
            if (__all((int)mine)) break;
            __builtin_amdgcn_s_sleep(1);
        }

        // ---- h MFMAs (weights from LDS, 4 chains) ----
#pragma unroll
        for (int ks = 0; ks < 4; ++ks) {
            union { unsigned long long qq[2]; bf16x8 v; } ua;
            ua.qq[0] = q[2*ks]; ua.qq[1] = q[2*ks+1];
            bf16x8 w0 = hw[wv][0][ks][lane];
            bf16x8 w1 = hw[wv][1][ks][lane];
            bf16x8 w2 = hw[wv][2][ks][lane];
            bf16x8 w3 = hw[wv][3][ks][lane];
            acc[0] = __builtin_amdgcn_mfma_f32_16x16x32_bf16(ua.v, w0, acc[0], 0, 0, 0);
            acc[1] = __builtin_amdgcn_mfma_f32_16x16x32_bf16(ua.v, w1, acc[1], 0, 0, 0);
            acc[2] = __builtin_amdgcn_mfma_f32_16x16x32_bf16(ua.v, w2, acc[2], 0, 0, 0);
            acc[3] = __builtin_amdgcn_mfma_f32_16x16x32_bf16(ua.v, w3, acc[3], 0, 0, 0);
        }

        // ---- cross-wave reduce: ds_add into the parity gate tile ----
        // (D layout: col = lane&15, row = kblk*4 + r; <=2-way banks in-wave)
#pragma unroll
        for (int g = 0; g < 4; ++g)
#pragma unroll
            for (int r = 0; r < 4; ++r)
                atomicAdd(&gbuf[t & 1][kblk * 4 + r][g * 16 + c], acc[g][r]);

        // ONE barrier per step. Implicit vmcnt/lgkm drain orders: all ds_adds
        // before reads; last tail's re-sentinel + x loads + y/h stores acked.
        __syncthreads();

        if (tid < 256) {
            // ---- epilogue (waves 0-3): read+zero gates, activations ----
            const int p = t & 1;
            float gi = gbuf[p][eb][ 0 + ej]; gbuf[p][eb][ 0 + ej] = 0.f;
            float gf = gbuf[p][eb][16 + ej]; gbuf[p][eb][16 + ej] = 0.f;
            float gg = gbuf[p][eb][32 + ej]; gbuf[p][eb][32 + ej] = 0.f;
            float go = gbuf[p][eb][48 + ej]; gbuf[p][eb][48 + ej] = 0.f;
            gi += bi; gf += bfv; gg += bgv; go += bo;

            float I = sigmoid_f(gi);
            float F = sigmoid_f(gf);
            float G = tanh_f(gg);
            float O = sigmoid_f(go);
            cstate = F * cstate + I * G;
            float hval = O * tanh_f(cstate);

            // h store = THE signal (packed 8B per 4 threads, coalesced)
            unsigned int mybf = (unsigned int)(unsigned short)f2bf(hval);
            unsigned int p01  = mybf | (((unsigned int)__shfl_xor((int)mybf, 1, 64)) << 16);
            unsigned int p23  = (unsigned int)__shfl_xor((int)p01, 2, 64);
            if ((t + 1 < T_) && (ej & 3) == 0) {
                unsigned long long pk = (unsigned long long)p01
                                      | ((unsigned long long)p23 << 32);
                unsigned long long* hp = hqb
                    + (((size_t)(((t + 1) & 3) * 4 + bt) * 128 + jt * 2 + (ej >> 3)) * 16
                       + eb) * 2 + ((ej >> 2) & 1);
                astoreq(hp, pk);
            }
            y[((size_t)b_glob * T_ + t) * H_ + j_glob] = hval;
        } else if (tid < 320 && t + 1 < T_) {
            // ---- wave 4: re-sentinel ring slot t+3 (own produced region) ----
            int sid = tid - 256;
            int qch = jt * 2 + (sid >> 5);
            int bb  = (sid >> 1) & 15;
            int hf  = sid & 1;
            unsigned long long* sp = hqb
                + (((size_t)(((t + 3) & 3) * 4 + bt) * 128 + qch) * 16 + bb) * 2 + hf;
            astoreq(sp, SENTQ);
        }

        // ---- tail (all waves): x(t+1) MFMAs from prefetched regs; issue x(t+2)
#pragma unroll
        for (int g = 0; g < 4; ++g)
            acc[g] = (f32x4){0.f,0.f,0.f,0.f};
        if (t + 1 < T_) {
#pragma unroll
            for (int ks = 0; ks < 2; ++ks) {
                bf16x8 xa;
#pragma unroll
                for (int e = 0; e < 4; ++e) { xa[e] = f2bf(xl[ks][e]); xa[e+4] = f2bf(xh[ks][e]); }
#pragma unroll
                for (int g = 0; g < 4; ++g)
                    acc[g] = __builtin_amdgcn_mfma_f32_16x16x32_bf16(xa, wxf[g][ks], acc[g], 0, 0, 0);
            }
        }
        if (t + 2 < T_) {
            const float* xr = x + ((size_t)b_a * T_ + (t + 2)) * D_ + kx0 + kblk * 8;
#pragma unroll
            for (int ks = 0; ks < 2; ++ks) {
                xl[ks] = *(const f32x4*)(xr + ks * 32);
                xh[ks] = *(const f32x4*)(xr + ks * 32 + 4);
            }
        }
    }
}

extern "C" void kernel_launch(void* const* d_in, const int* in_sizes, int n_in,
                              void* d_out, int out_size, void* d_ws, size_t ws_size,
                              hipStream_t stream)
{
    const float* x    = (const float*)d_in[0];
    const float* Wx   = (const float*)d_in[1];
    const float* Wh   = (const float*)d_in[2];
    const float* bias = (const float*)d_in[3];
    float* y = (float*)d_out;

    short* h_buf = (short*)d_ws;   // 4 slots x 4 groups x 128 q x 16 b x 8 = 512 KB

    // Re-init the ring every call (replay-safe): slot0 = h_0 = zeros,
    // slots1..3 = sentinel.
    init_hbuf<<<dim3((4 * B_ * H_ / 2) / 256), dim3(256), 0, stream>>>(
        (unsigned int*)h_buf);

    lstm_persistent<<<dim3(NWG), dim3(WTH), 0, stream>>>(
        x, Wx, Wh, bias, y, h_buf);
}

// Round 12
// 3226.232 us; speedup vs baseline: 4.1388x; 4.1388x over previous
//
#include <hip/hip_runtime.h>
#include <hip/hip_bf16.h>

#define B_  64
#define T_  1024
#define D_  512
#define H_  1024
#define G4H (4 * H_)
#define NWG 256
#define SENTQ 0x7FC07FC07FC07FC0ull   // bf16 NaN x4: unreachable, |h|<1

typedef __attribute__((ext_vector_type(8))) short bf16x8;
typedef __attribute__((ext_vector_type(4))) float f32x4;

__device__ __forceinline__ short f2bf(float f) {
    union { float f; unsigned int u; } v; v.f = f;
    unsigned int r = v.u + 0x7FFFu + ((v.u >> 16) & 1u);  // RNE
    return (short)(r >> 16);
}
__device__ __forceinline__ float sigmoid_f(float x) { return 1.0f / (1.0f + __expf(-x)); }
__device__ __forceinline__ float tanh_f(float x) {
    float ax = fabsf(x);
    float e  = __expf(-2.0f * ax);
    return copysignf((1.0f - e) / (1.0f + e), x);
}
__device__ __forceinline__ unsigned long long aloadq(const unsigned long long* p) {
    return __hip_atomic_load(p, __ATOMIC_RELAXED, __HIP_MEMORY_SCOPE_AGENT);
}
__device__ __forceinline__ void astoreq(unsigned long long* p, unsigned long long v) {
    __hip_atomic_store(p, v, __ATOMIC_RELAXED, __HIP_MEMORY_SCOPE_AGENT);
}

// init: slot0 = 0.0 (this IS h_0), slots1..3 = sentinel.
__global__ void init_hbuf(unsigned int* p) {
    int i = blockIdx.x * 256 + threadIdx.x;       // 131072 u32
    p[i] = (i < (B_ * H_ / 2)) ? 0u : 0x7FC07FC0u;
}

// R12 = R10 (best measured: 3.28ms; coalesced sentinel ring, 4-wave WGs,
// IC agent path) + two serial-term cuts, after R11 disproved occupancy:
//  (1) sync2 -> RAW barrier (lgkmcnt only): its WAR hazard (gbuf reads vs
//      next iter writes) needs LDS completion, not the vmcnt(0) drain of the
//      just-issued h/y stores (~400-500cy saved). sync1 keeps the full drain
//      -> all sentinel-before-data ordering proofs unchanged.
//  (2) x-MFMAs moved INTO the poll shadow: issue 16 poll loads, run the
//      register-only x-part while they fly, then check (vmcnt waits at first
//      use). Hides ~250cy instead of delaying poll start from the tail.
__global__ void __launch_bounds__(256, 1)
lstm_persistent(const float* __restrict__ x,     // [B,T,D]
                const float* __restrict__ Wx,    // [D,4H]
                const float* __restrict__ Wh,    // [H,4H]
                const float* __restrict__ bias,  // [4H] (i,f,g,o)
                float* __restrict__ y,           // [B,T,H]
                short* __restrict__ h_buf)       // ws: [4][4][128][16][8] bf16
{
    const int wg   = blockIdx.x;
    const int tid  = threadIdx.x;
    const int lane = tid & 63;
    const int wv   = tid >> 6;
    const int bt   = (wg >> 1) & 3;               // batch group 0..3
    const int jt   = ((wg & 1) << 5) | (wg >> 3); // hidden tile 0..63
    const int j0   = jt * 16;

    const int c    = lane & 15;         // A-row (in-group batch) / B-col
    const int kblk = lane >> 4;         // k-block (8 contiguous k)
    const int b_a  = bt * 16 + c;       // global batch for x A-frags
    const int kh0  = wv * 256;          // wave's K-slice of H
    const int kx0  = wv * 128;          // wave's K-slice of D

    unsigned long long* const hqb = (unsigned long long*)h_buf;

    __shared__ bf16x8 hw[4][4][8][64];  // 128 KB: [wv][gate][ks][lane]
    __shared__ float  gbuf[4][16][67];  // partial-gate tiles

    // ---- prologue: h-weights -> LDS (each thread fills/reads its own slot)
#pragma unroll
    for (int g = 0; g < 4; ++g)
#pragma unroll
        for (int ks = 0; ks < 8; ++ks) {
            bf16x8 tf;
#pragma unroll
            for (int e = 0; e < 8; ++e)
                tf[e] = f2bf(Wh[(size_t)(kh0 + ks * 32 + kblk * 8 + e) * G4H
                                + g * H_ + j0 + c]);
            hw[wv][g][ks][lane] = tf;
        }

    // ---- x-weights -> registers (64 VGPRs), pinned vs rematerialization
    bf16x8 wxf[4][4];
#pragma unroll
    for (int g = 0; g < 4; ++g)
#pragma unroll
        for (int ks = 0; ks < 4; ++ks) {
            bf16x8 tf;
#pragma unroll
            for (int e = 0; e < 8; ++e)
                tf[e] = f2bf(Wx[(size_t)(kx0 + ks * 32 + kblk * 8 + e) * G4H
                                + g * H_ + j0 + c]);
            wxf[g][ks] = tf;
        }
#pragma unroll
    for (int g = 0; g < 4; ++g)
#pragma unroll
        for (int ks = 0; ks < 4; ++ks)
            asm volatile("" : "+v"(wxf[g][ks]));   // opaque: cannot re-load

    // ---- epilogue mapping: thread -> one (batch eb, hidden ej)
    const int eb = tid >> 4;
    const int ej = tid & 15;
    const float bi  = bias[0 * H_ + j0 + ej];
    const float bfv = bias[1 * H_ + j0 + ej];
    const float bgv = bias[2 * H_ + j0 + ej];
    const float bo  = bias[3 * H_ + j0 + ej];
    const int b_glob = bt * 16 + eb;
    const int j_glob = j0 + ej;

    float cstate = 0.0f;

    // ---- prefetch x(0) into registers (consumed in iter 0's poll shadow)
    f32x4 xl[4], xh[4];
    {
        const float* xr = x + ((size_t)b_a * T_ + 0) * D_ + kx0 + kblk * 8;
#pragma unroll
        for (int ks = 0; ks < 4; ++ks) {
            xl[ks] = *(const f32x4*)(xr + ks * 32);
            xh[ks] = *(const f32x4*)(xr + ks * 32 + 4);
        }
    }

#pragma unroll 1
    for (int t = 0; t < T_; ++t) {
        // ---- (1) issue poll round for h_t (coalesced; data IS the flag) ----
        const unsigned long long* hq = hqb
            + ((((size_t)(t & 3) * 4 + bt) * 128 + wv * 32 + kblk) * 16 + c) * 2;
        unsigned long long q[16];
#pragma unroll
        for (int ks = 0; ks < 8; ++ks) {
            q[2*ks]   = aloadq(hq + ks * 128);      // ks stride = 4 chunks
            q[2*ks+1] = aloadq(hq + ks * 128 + 1);
        }

        // ---- (2) x-part in the poll shadow (register-only MFMAs) ----
        f32x4 acc[4] = {{0.f,0.f,0.f,0.f},{0.f,0.f,0.f,0.f},
                        {0.f,0.f,0.f,0.f},{0.f,0.f,0.f,0.f}};
#pragma unroll
        for (int ks = 0; ks < 4; ++ks) {
            bf16x8 xa;
#pragma unroll
            for (int e = 0; e < 4; ++e) { xa[e] = f2bf(xl[ks][e]); xa[e+4] = f2bf(xh[ks][e]); }
#pragma unroll
            for (int g = 0; g < 4; ++g)
                acc[g] = __builtin_amdgcn_mfma_f32_16x16x32_bf16(xa, wxf[g][ks], acc[g], 0, 0, 0);
        }

        // ---- (3) check / spin (bounded) ----
        for (int cap = 1 << 18; cap > 0; --cap) {
            bool mine = true;
#pragma unroll
            for (int i = 0; i < 16; ++i) mine &= (q[i] != SENTQ);
            if (__all((int)mine)) break;
            __builtin_amdgcn_s_sleep(1);
#pragma unroll
            for (int ks = 0; ks < 8; ++ks) {
                q[2*ks]   = aloadq(hq + ks * 128);
                q[2*ks+1] = aloadq(hq + ks * 128 + 1);
            }
        }

        // ---- (4) h MFMAs (weights from LDS, 4 chains) ----
#pragma unroll
        for (int ks = 0; ks < 8; ++ks) {
            union { unsigned long long qq[2]; bf16x8 v; } ua;
            ua.qq[0] = q[2*ks]; ua.qq[1] = q[2*ks+1];   // k = 8q..8q+7
            bf16x8 w0 = hw[wv][0][ks][lane];
            bf16x8 w1 = hw[wv][1][ks][lane];
            bf16x8 w2 = hw[wv][2][ks][lane];
            bf16x8 w3 = hw[wv][3][ks][lane];
            acc[0] = __builtin_amdgcn_mfma_f32_16x16x32_bf16(ua.v, w0, acc[0], 0, 0, 0);
            acc[1] = __builtin_amdgcn_mfma_f32_16x16x32_bf16(ua.v, w1, acc[1], 0, 0, 0);
            acc[2] = __builtin_amdgcn_mfma_f32_16x16x32_bf16(ua.v, w2, acc[2], 0, 0, 0);
            acc[3] = __builtin_amdgcn_mfma_f32_16x16x32_bf16(ua.v, w3, acc[3], 0, 0, 0);
        }

        // ---- (5) partials -> LDS (D layout: col=lane&15, row=kblk*4+r) ----
#pragma unroll
        for (int g = 0; g < 4; ++g)
#pragma unroll
            for (int r = 0; r < 4; ++r)
                gbuf[wv][kblk * 4 + r][g * 16 + c] = acc[g][r];
        // sync1 (FULL drain, via __syncthreads): orders last iter's tail
        // stores (incl. re-sentinel of slot t+2) before this iter's h store.
        __syncthreads();

        // ---- (6) reduce 4 wave-partials + activations ----
        float gi = ((gbuf[0][eb][ 0+ej] + gbuf[1][eb][ 0+ej])
                  + (gbuf[2][eb][ 0+ej] + gbuf[3][eb][ 0+ej])) + bi;
        float gf = ((gbuf[0][eb][16+ej] + gbuf[1][eb][16+ej])
                  + (gbuf[2][eb][16+ej] + gbuf[3][eb][16+ej])) + bfv;
        float gg = ((gbuf[0][eb][32+ej] + gbuf[1][eb][32+ej])
                  + (gbuf[2][eb][32+ej] + gbuf[3][eb][32+ej])) + bgv;
        float go = ((gbuf[0][eb][48+ej] + gbuf[1][eb][48+ej])
                  + (gbuf[2][eb][48+ej] + gbuf[3][eb][48+ej])) + bo;

        float I = sigmoid_f(gi);
        float F = sigmoid_f(gf);
        float G = tanh_f(gg);
        float O = sigmoid_f(go);
        cstate = F * cstate + I * G;
        float hval = O * tanh_f(cstate);

        // ---- (7) h store = THE signal (packed 8B per 4 threads) ----
        unsigned int mybf = (unsigned int)(unsigned short)f2bf(hval);
        unsigned int p01  = mybf | (((unsigned int)__shfl_xor((int)mybf, 1, 64)) << 16);
        unsigned int p23  = (unsigned int)__shfl_xor((int)p01, 2, 64);
        if ((t + 1 < T_) && (ej & 3) == 0) {
            unsigned long long pk = (unsigned long long)p01
                                  | ((unsigned long long)p23 << 32);
            unsigned long long* hp = hqb
                + (((size_t)(((t + 1) & 3) * 4 + bt) * 128 + jt * 2 + (ej >> 3)) * 16
                   + eb) * 2 + ((ej >> 2) & 1);
            astoreq(hp, pk);
        }

        // ---- sync2: RAW barrier (LDS-only wait). gbuf WAR needs lgkmcnt
        // only; the h/y store acks drain at sync1(t+1) instead (~450cy cut).
        asm volatile("s_waitcnt lgkmcnt(0)\n\ts_barrier" ::: "memory");

        // ---- (8) tail (off critical path): y, re-sentinel t+3, x(t+1) ----
        y[((size_t)b_glob * T_ + t) * H_ + j_glob] = hval;   // 64B / 16 lanes

        // re-sentinel ring slot t+3 (own produced region; consumers provably
        // done: seeing h_t implies every WG finished its slot-(t-1) reads).
        // Drained by sync1(t+1) -> lands before our slot-(t+3) data store.
        if (t + 1 < T_ && tid < 64) {
            int qch = jt * 2 + (tid >> 5);
            int bb  = (tid >> 1) & 15;
            int hf  = tid & 1;
            unsigned long long* sp = hqb
                + (((size_t)(((t + 3) & 3) * 4 + bt) * 128 + qch) * 16 + bb) * 2 + hf;
            astoreq(sp, SENTQ);
        }

        if (t + 1 < T_) {
            const float* xr = x + ((size_t)b_a * T_ + (t + 1)) * D_ + kx0 + kblk * 8;
#pragma unroll
            for (int ks = 0; ks < 4; ++ks) {
                xl[ks] = *(const f32x4*)(xr + ks * 32);
                xh[ks] = *(const f32x4*)(xr + ks * 32 + 4);
            }
        }
    }
}

extern "C" void kernel_launch(void* const* d_in, const int* in_sizes, int n_in,
                              void* d_out, int out_size, void* d_ws, size_t ws_size,
                              hipStream_t stream)
{
    const float* x    = (const float*)d_in[0];
    const float* Wx   = (const float*)d_in[1];
    const float* Wh   = (const float*)d_in[2];
    const float* bias = (const float*)d_in[3];
    float* y = (float*)d_out;

    short* h_buf = (short*)d_ws;   // 4 slots x 4 groups x 128 q x 16 b x 8 = 512 KB

    // Re-init the ring every call (replay-safe): slot0 = h_0 = zeros,
    // slots1..3 = sentinel.
    init_hbuf<<<dim3((4 * B_ * H_ / 2) / 256), dim3(256), 0, stream>>>(
        (unsigned int*)h_buf);

    lstm_persistent<<<dim3(NWG), dim3(256), 0, stream>>>(
        x, Wx, Wh, bias, y, h_buf);
}